// Round 4
// baseline (276.153 us; speedup 1.0000x reference)
//
#include <hip/hip_runtime.h>
#include <string.h>
#include <math.h>

typedef unsigned short u16;
typedef __bf16 bf16x8 __attribute__((ext_vector_type(8)));
typedef float floatx4 __attribute__((ext_vector_type(4)));

#define HEADS  16
#define DH     64
#define BATCH  2
#define NQ     512
#define NKV    4096
#define DMODEL 1024
#define INNER  1024
#define SCALE  0.125f
#define LOG2E  1.4426950408889634f
#define SPLIT  4
#define KEYS_PER_PART (NKV / SPLIT)
#define CH (KEYS_PER_PART / 64)

__device__ __forceinline__ u16 f2bf(float f) {
  union { float f; unsigned int u; } v; v.f = f;
  unsigned int u = v.u;
  unsigned int r = u + 0x7fffu + ((u >> 16) & 1u);   // RNE
  return (u16)(r >> 16);
}

// async global->LDS, 16B per lane; LDS dest = wave-uniform base + lane*16
__device__ __forceinline__ void gll16(const u16* g, u16* l) {
  __builtin_amdgcn_global_load_lds(
      (const __attribute__((address_space(1))) unsigned int*)g,
      (__attribute__((address_space(3))) unsigned int*)l, 16, 0, 0);
}

// ---------------- fp32 -> bf16 convert, 8 elems/thread ----------------
__global__ __launch_bounds__(256) void conv_bf16(const float* __restrict__ x,
                                                 u16* __restrict__ y) {
  const size_t i = (size_t)blockIdx.x * 256 + threadIdx.x;
  const float4* p = (const float4*)x + i * 2;
  float4 a = p[0], b = p[1];
  union { u16 s[8]; uint4 q; } o;
  o.s[0] = f2bf(a.x); o.s[1] = f2bf(a.y); o.s[2] = f2bf(a.z); o.s[3] = f2bf(a.w);
  o.s[4] = f2bf(b.x); o.s[5] = f2bf(b.y); o.s[6] = f2bf(b.z); o.s[7] = f2bf(b.w);
  *(uint4*)(y + i * 8) = o.q;
}

// ---------------- transpose+convert: Wt[n][k] = bf16(W[k][n]), W is KxN ----
__global__ __launch_bounds__(256) void transpose_conv(const float* __restrict__ W,
                                                      u16* __restrict__ Wt,
                                                      int K, int N) {
  __shared__ float tile[32][33];
  const int tx = threadIdx.x & 31, ty = threadIdx.x >> 5;  // 32x8
  const int n0 = blockIdx.x * 32, k0 = blockIdx.y * 32;
  for (int i = 0; i < 32; i += 8)
    tile[ty + i][tx] = W[(size_t)(k0 + ty + i) * N + n0 + tx];
  __syncthreads();
  for (int i = 0; i < 32; i += 8)
    Wt[(size_t)(n0 + ty + i) * K + k0 + tx] = f2bf(tile[tx][ty + i]);
}

// ---------------- GEMM 128x128: C[MxN] = A[MxK](bf16) * Bt[NxK]^T ----------
template<bool OUT_BF16>
__global__ __launch_bounds__(256) void gemm_bt(const u16* __restrict__ A,
                                               const u16* __restrict__ Bt,
                                               float* __restrict__ Cf,
                                               u16* __restrict__ Cb,
                                               const float* __restrict__ bias,
                                               int M, int N, int K) {
  __shared__ __align__(16) u16 As[128 * 32];
  __shared__ __align__(16) u16 Bs[128 * 32];
  const int tid  = threadIdx.x;
  const int lane = tid & 63, wave = tid >> 6;
  const int wr = wave >> 1, wc = wave & 1;
  const int l16 = lane & 15, quad = lane >> 4;
  const int bm = blockIdx.y, bn = blockIdx.x;
  const int r0 = tid >> 2;
  const int kb = (tid & 3) ^ ((tid >> 3) & 3);     // swizzled k-block
  const u16* aP0 = A  + ((size_t)bm * 128 + r0)      * K + kb * 8;
  const u16* aP1 = A  + ((size_t)bm * 128 + r0 + 64) * K + kb * 8;
  const u16* bP0 = Bt + ((size_t)bn * 128 + r0)      * K + kb * 8;
  const u16* bP1 = Bt + ((size_t)bn * 128 + r0 + 64) * K + kb * 8;
  u16* ldsA0 = As + wave * 512;
  u16* ldsA1 = As + 2048 + wave * 512;
  u16* ldsB0 = Bs + wave * 512;
  u16* ldsB1 = Bs + 2048 + wave * 512;
  const int ko = ((quad ^ ((l16 >> 1) & 3)) << 3);

  floatx4 acc[4][4] = {};
  for (int k0 = 0; k0 < K; k0 += 32) {
    gll16(aP0 + k0, ldsA0);
    gll16(aP1 + k0, ldsA1);
    gll16(bP0 + k0, ldsB0);
    gll16(bP1 + k0, ldsB1);
    __syncthreads();
    bf16x8 af[4], bfr[4];
#pragma unroll
    for (int i = 0; i < 4; ++i)
      af[i] = *(const bf16x8*)&As[(wr * 64 + i * 16 + l16) * 32 + ko];
#pragma unroll
    for (int j = 0; j < 4; ++j)
      bfr[j] = *(const bf16x8*)&Bs[(wc * 64 + j * 16 + l16) * 32 + ko];
#pragma unroll
    for (int i = 0; i < 4; ++i)
#pragma unroll
      for (int j = 0; j < 4; ++j)
        acc[i][j] = __builtin_amdgcn_mfma_f32_16x16x32_bf16(af[i], bfr[j], acc[i][j], 0, 0, 0);
    __syncthreads();
  }
#pragma unroll
  for (int i = 0; i < 4; ++i) {
    const int rowb = bm * 128 + wr * 64 + i * 16 + quad * 4;
#pragma unroll
    for (int j = 0; j < 4; ++j) {
      const int col = bn * 128 + wc * 64 + j * 16 + l16;
#pragma unroll
      for (int r = 0; r < 4; ++r) {
        const size_t idx = (size_t)(rowb + r) * N + col;
        if (OUT_BF16) Cb[idx] = f2bf(acc[i][j][r]);
        else          Cf[idx] = acc[i][j][r] + bias[col];
      }
    }
  }
}

// ---------------- GEMM 64x64 tile (for small M,N: more blocks) ----------
// 4 waves in 2x2 quadrants of 32x32; BK=64; XOR swizzle cb^=(row&7).
template<bool OUT_BF16>
__global__ __launch_bounds__(256) void gemm64(const u16* __restrict__ A,
                                              const u16* __restrict__ Bt,
                                              float* __restrict__ Cf,
                                              u16* __restrict__ Cb,
                                              const float* __restrict__ bias,
                                              int M, int N, int K) {
  __shared__ __align__(16) u16 As[64 * 64];
  __shared__ __align__(16) u16 Bs[64 * 64];
  const int tid = threadIdx.x;
  const int lane = tid & 63, wave = tid >> 6;
  const int wr = wave >> 1, wc = wave & 1;
  const int l16 = lane & 15, quad = lane >> 4;
  const int bm = blockIdx.y, bn = blockIdx.x;
  const int r0 = tid >> 3;                       // rows 0..31 (inst0), +32 (inst1)
  const int kbs = (tid & 7) ^ (r0 & 7);          // swizzled k-block (global col)
  const u16* aP0 = A  + ((size_t)bm * 64 + r0)      * K + kbs * 8;
  const u16* aP1 = A  + ((size_t)bm * 64 + r0 + 32) * K + kbs * 8;
  const u16* bP0 = Bt + ((size_t)bn * 64 + r0)      * K + kbs * 8;
  const u16* bP1 = Bt + ((size_t)bn * 64 + r0 + 32) * K + kbs * 8;
  u16* ldsA0 = As + wave * 512;
  u16* ldsA1 = As + 2048 + wave * 512;
  u16* ldsB0 = Bs + wave * 512;
  u16* ldsB1 = Bs + 2048 + wave * 512;

  floatx4 acc[2][2] = {};
  for (int k0 = 0; k0 < K; k0 += 64) {
    gll16(aP0 + k0, ldsA0);
    gll16(aP1 + k0, ldsA1);
    gll16(bP0 + k0, ldsB0);
    gll16(bP1 + k0, ldsB1);
    __syncthreads();
    bf16x8 af[2][2], bfr[2][2];
#pragma unroll
    for (int i = 0; i < 2; ++i)
#pragma unroll
      for (int kk = 0; kk < 2; ++kk)
        af[i][kk] = *(const bf16x8*)&As[(wr * 32 + i * 16 + l16) * 64 +
                                        (((kk * 4 + quad) ^ (l16 & 7)) << 3)];
#pragma unroll
    for (int j = 0; j < 2; ++j)
#pragma unroll
      for (int kk = 0; kk < 2; ++kk)
        bfr[j][kk] = *(const bf16x8*)&Bs[(wc * 32 + j * 16 + l16) * 64 +
                                         (((kk * 4 + quad) ^ (l16 & 7)) << 3)];
#pragma unroll
    for (int i = 0; i < 2; ++i)
#pragma unroll
      for (int j = 0; j < 2; ++j) {
        acc[i][j] = __builtin_amdgcn_mfma_f32_16x16x32_bf16(af[i][0], bfr[j][0], acc[i][j], 0, 0, 0);
        acc[i][j] = __builtin_amdgcn_mfma_f32_16x16x32_bf16(af[i][1], bfr[j][1], acc[i][j], 0, 0, 0);
      }
    __syncthreads();
  }
#pragma unroll
  for (int i = 0; i < 2; ++i) {
    const int rowb = bm * 64 + wr * 32 + i * 16 + quad * 4;
#pragma unroll
    for (int j = 0; j < 2; ++j) {
      const int col = bn * 64 + wc * 32 + j * 16 + l16;
#pragma unroll
      for (int r = 0; r < 4; ++r) {
        const size_t idx = (size_t)(rowb + r) * N + col;
        if (OUT_BF16) Cb[idx] = f2bf(acc[i][j][r]);
        else          Cf[idx] = acc[i][j][r] + bias[col];
      }
    }
  }
}

// ---------------- flash attention, split-K partials (pipelined) ----------
// blockIdx = qt*128 + g, g=(b*64 + h*4 + part): qt-tiles sharing KV land on
// one XCD. Reg-prefetch of next chunk's K/V/mask overlaps global latency.
__global__ __launch_bounds__(256) void attn_part(const u16* __restrict__ Qh,
                                                 const u16* __restrict__ KVp,
                                                 const int* __restrict__ mask,
                                                 float* __restrict__ Opart,
                                                 float* __restrict__ Mst,
                                                 float* __restrict__ Lst) {
  __shared__ u16 Ks[64 * 72];
  __shared__ u16 Vs[64 * 72];     // transposed: Vs[d][key]
  __shared__ u16 QP[4864];        // Qs (stride 72) then Ps[4] (stride 76)
  __shared__ float Msk[64];
  const int tid = threadIdx.x;
  const int lane = tid & 63, w = tid >> 6;
  const int l16 = lane & 15, quad = lane >> 4;
  const int g  = blockIdx.x & 127;
  const int qt = blockIdx.x >> 7;
  const int part = g & 3;
  const int h  = (g >> 2) & 15;
  const int b  = g >> 6;
  const int krs = tid >> 2, kd0 = (tid & 3) * 16;   // K staging map
  const int kp  = tid & 31, dh8 = tid >> 5;          // V staging: keys 2kp,2kp+1; d=dh8*8..+7
  u16* Ps = QP + w * 1216;        // 16 rows * stride 76

  { // stage Q tile (64 x 64), stride 72
    const uint4* p = (const uint4*)(Qh + ((size_t)(b * NQ + qt * 64 + krs)) * INNER + h * DH + kd0);
    *(uint4*)&QP[krs * 72 + kd0]     = p[0];
    *(uint4*)&QP[krs * 72 + kd0 + 8] = p[1];
  }
  __syncthreads();
  bf16x8 aq0 = *(const bf16x8*)&QP[(w * 16 + l16) * 72 + quad * 8];
  bf16x8 aq1 = *(const bf16x8*)&QP[(w * 16 + l16) * 72 + 32 + quad * 8];
  __syncthreads();   // all waves done reading Q before QP is reused as Ps

  floatx4 o[4] = {};
  float m_r[4] = {-1e30f, -1e30f, -1e30f, -1e30f};
  float l_r[4] = {0.f, 0.f, 0.f, 0.f};

  const int key00 = part * KEYS_PER_PART;
  uint4 kr0, kr1, vr0, vr1;
  float mkreg = 0.f;
  const size_t kvstride = 2 * INNER;

  auto prefetch = [&](int c) {
    const int key0 = key00 + c * 64;
    const u16* kbase = KVp + ((size_t)(b * NKV + key0 + krs)) * kvstride + h * DH + kd0;
    kr0 = ((const uint4*)kbase)[0];
    kr1 = ((const uint4*)kbase)[1];
    const u16* vbase = KVp + ((size_t)(b * NKV + key0 + 2 * kp)) * kvstride + INNER + h * DH + dh8 * 8;
    vr0 = *(const uint4*)vbase;
    vr1 = *(const uint4*)(vbase + kvstride);
    if (tid < 64) mkreg = (mask[(size_t)b * NKV + key0 + tid] != 0) ? 0.0f : -1e30f;
  };
  prefetch(0);

  for (int c = 0; c < CH; ++c) {
    __syncthreads();   // all waves done computing previous chunk
    // ---- stage from regs ----
    *(uint4*)&Ks[krs * 72 + kd0]     = kr0;
    *(uint4*)&Ks[krs * 72 + kd0 + 8] = kr1;
    {
      union { uint4 q; u16 s[8]; } va, vb;
      va.q = vr0; vb.q = vr1;
#pragma unroll
      for (int i = 0; i < 8; ++i) {
        unsigned int pack = (unsigned int)va.s[i] | ((unsigned int)vb.s[i] << 16);
        *(unsigned int*)&Vs[(dh8 * 8 + i) * 72 + 2 * kp] = pack;
      }
    }
    if (tid < 64) Msk[tid] = mkreg;
    __syncthreads();
    if (c + 1 < CH) prefetch(c + 1);

    // ---- S = Q K^T ----
    float sv[4][4];
#pragma unroll
    for (int nt = 0; nt < 4; ++nt) {
      bf16x8 b0 = *(const bf16x8*)&Ks[(nt * 16 + l16) * 72 + quad * 8];
      bf16x8 b1 = *(const bf16x8*)&Ks[(nt * 16 + l16) * 72 + 32 + quad * 8];
      floatx4 t = {0.f, 0.f, 0.f, 0.f};
      t = __builtin_amdgcn_mfma_f32_16x16x32_bf16(aq0, b0, t, 0, 0, 0);
      t = __builtin_amdgcn_mfma_f32_16x16x32_bf16(aq1, b1, t, 0, 0, 0);
      const float mk = Msk[nt * 16 + l16];
#pragma unroll
      for (int r = 0; r < 4; ++r) sv[nt][r] = t[r] * (SCALE * LOG2E) + mk;  // log2 domain
    }
    // ---- row stats (row = quad*4+r across 16 lanes of the quad) ----
    float mnew[4], alpha[4], psum[4];
#pragma unroll
    for (int r = 0; r < 4; ++r) {
      float t = fmaxf(fmaxf(sv[0][r], sv[1][r]), fmaxf(sv[2][r], sv[3][r]));
      t = fmaxf(t, __shfl_xor(t, 1));
      t = fmaxf(t, __shfl_xor(t, 2));
      t = fmaxf(t, __shfl_xor(t, 4));
      t = fmaxf(t, __shfl_xor(t, 8));
      mnew[r] = fmaxf(m_r[r], t);
      alpha[r] = exp2f(m_r[r] - mnew[r]);
      m_r[r] = mnew[r];
      psum[r] = 0.f;
    }
    // ---- P = 2^(S-m) -> Ps (stride 76), row sums ----
#pragma unroll
    for (int nt = 0; nt < 4; ++nt)
#pragma unroll
      for (int r = 0; r < 4; ++r) {
        float p = exp2f(sv[nt][r] - mnew[r]);
        psum[r] += p;
        Ps[(quad * 4 + r) * 76 + nt * 16 + l16] = f2bf(p);
      }
#pragma unroll
    for (int r = 0; r < 4; ++r) {
      float t = psum[r];
      t += __shfl_xor(t, 1);
      t += __shfl_xor(t, 2);
      t += __shfl_xor(t, 4);
      t += __shfl_xor(t, 8);
      l_r[r] = l_r[r] * alpha[r] + t;
#pragma unroll
      for (int dt = 0; dt < 4; ++dt) o[dt][r] *= alpha[r];
    }
    // ---- O += P V ----
    bf16x8 ap0 = *(const bf16x8*)&Ps[l16 * 76 + quad * 8];
    bf16x8 ap1 = *(const bf16x8*)&Ps[l16 * 76 + 32 + quad * 8];
#pragma unroll
    for (int dt = 0; dt < 4; ++dt) {
      bf16x8 bv0 = *(const bf16x8*)&Vs[(dt * 16 + l16) * 72 + quad * 8];
      bf16x8 bv1 = *(const bf16x8*)&Vs[(dt * 16 + l16) * 72 + 32 + quad * 8];
      o[dt] = __builtin_amdgcn_mfma_f32_16x16x32_bf16(ap0, bv0, o[dt], 0, 0, 0);
      o[dt] = __builtin_amdgcn_mfma_f32_16x16x32_bf16(ap1, bv1, o[dt], 0, 0, 0);
    }
  }
  // ---- epilogue: unnormalized partial O + stats ----
  const int pid = ((b * 128 + h * 8 + qt) << 2) + part;
#pragma unroll
  for (int r = 0; r < 4; ++r) {
    const int q = w * 16 + quad * 4 + r;
    if (l16 == 0) { Mst[pid * 64 + q] = m_r[r]; Lst[pid * 64 + q] = l_r[r]; }
#pragma unroll
    for (int dt = 0; dt < 4; ++dt)
      Opart[(size_t)pid * 4096 + q * 64 + dt * 16 + l16] = o[dt][r];
  }
}

// ---------------- combine split-K partials ----------------
__global__ __launch_bounds__(256) void attn_combine(const float* __restrict__ Opart,
                                                    const float* __restrict__ Mst,
                                                    const float* __restrict__ Lst,
                                                    u16* __restrict__ Out) {
  const int x = blockIdx.x;
  const int t = threadIdx.x;
  const int q = t >> 2, db = (t & 3) * 16;
  const int b = x >> 7, h = (x >> 3) & 15, qt = x & 7;
  float ms[SPLIT], ls[SPLIT];
#pragma unroll
  for (int s = 0; s < SPLIT; ++s) {
    ms[s] = Mst[(size_t)(x * SPLIT + s) * 64 + q];
    ls[s] = Lst[(size_t)(x * SPLIT + s) * 64 + q];
  }
  float M = fmaxf(fmaxf(ms[0], ms[1]), fmaxf(ms[2], ms[3]));
  float wgt[SPLIT], L = 0.f;
#pragma unroll
  for (int s = 0; s < SPLIT; ++s) { wgt[s] = exp2f(ms[s] - M); L += wgt[s] * ls[s]; }
  const float inv = 1.0f / L;
  float acc[16] = {};
#pragma unroll
  for (int s = 0; s < SPLIT; ++s) {
    const float4* p = (const float4*)&Opart[(size_t)(x * SPLIT + s) * 4096 + q * 64 + db];
    const float ws = wgt[s];
#pragma unroll
    for (int i = 0; i < 4; ++i) {
      float4 v = p[i];
      acc[i * 4 + 0] += ws * v.x; acc[i * 4 + 1] += ws * v.y;
      acc[i * 4 + 2] += ws * v.z; acc[i * 4 + 3] += ws * v.w;
    }
  }
  union { u16 s[16]; uint4 v[2]; } ou;
#pragma unroll
  for (int i = 0; i < 16; ++i) ou.s[i] = f2bf(acc[i] * inv);
  u16* dst = Out + ((size_t)(b * NQ + qt * 64 + q)) * INNER + h * DH + db;
  *(uint4*)dst = ou.v[0]; *(uint4*)(dst + 8) = ou.v[1];
}

// ---------------- launcher ----------------
extern "C" void kernel_launch(void* const* d_in, const int* in_sizes, int n_in,
                              void* d_out, int out_size, void* d_ws, size_t ws_size,
                              hipStream_t stream) {
  const float* q    = (const float*)d_in[0];
  const float* kv   = (const float*)d_in[1];
  const int*   mask = (const int*)d_in[2];
  const float* Wq   = (const float*)d_in[3];
  const float* Wkv  = (const float*)d_in[4];
  const float* Wo   = (const float*)d_in[5];
  const float* bo   = (const float*)d_in[6];
  float* out = (float*)d_out;

  char* ws = (char*)d_ws;
  u16*   qb    = (u16*)(ws);                     // 2MB  (dead after q-proj)
  u16*   kvb   = (u16*)(ws + (2u  << 20));       // 16MB (dead after kv-proj)
  float* Mst   = (float*)(ws);                   // aliases qb
  float* Lst   = (float*)(ws + (1u  << 20));     // aliases qb
  float* Opart = (float*)(ws + (2u  << 20));     // aliases kvb
  u16* Wqt  = (u16*)(ws + (18u << 20));
  u16* Wkvt = (u16*)(ws + (20u << 20));
  u16* Wot  = (u16*)(ws + (24u << 20));
  u16* qh   = (u16*)(ws + (26u << 20));
  u16* kvp  = (u16*)(ws + (28u << 20));
  u16* attn = (u16*)(ws + (60u << 20));

  conv_bf16<<<dim3((BATCH * NQ * DMODEL) / 2048), 256, 0, stream>>>(q, qb);
  conv_bf16<<<dim3((BATCH * NKV * DMODEL) / 2048), 256, 0, stream>>>(kv, kvb);
  transpose_conv<<<dim3(INNER / 32, DMODEL / 32), 256, 0, stream>>>(Wq, Wqt, DMODEL, INNER);
  transpose_conv<<<dim3(2 * INNER / 32, DMODEL / 32), 256, 0, stream>>>(Wkv, Wkvt, DMODEL, 2 * INNER);
  transpose_conv<<<dim3(DMODEL / 32, INNER / 32), 256, 0, stream>>>(Wo, Wot, INNER, DMODEL);

  // qh = qb @ Wq (1024x1024x1024) -- 64-tile: 256 blocks
  gemm64<true><<<dim3(INNER / 64, (BATCH * NQ) / 64), 256, 0, stream>>>(
      qb, Wqt, nullptr, qh, nullptr, BATCH * NQ, INNER, DMODEL);
  // kvp = kvb @ Wkv (8192x2048x1024) -- 128-tile: 1024 blocks
  gemm_bt<true><<<dim3((2 * INNER) / 128, (BATCH * NKV) / 128), 256, 0, stream>>>(
      kvb, Wkvt, nullptr, kvp, nullptr, BATCH * NKV, 2 * INNER, DMODEL);
  // attention: split-K partials + combine
  attn_part<<<dim3(BATCH * HEADS * (NQ / 64) * SPLIT), 256, 0, stream>>>(
      qh, kvp, mask, Opart, Mst, Lst);
  attn_combine<<<dim3(BATCH * HEADS * (NQ / 64)), 256, 0, stream>>>(Opart, Mst, Lst, attn);
  // out = attn @ Wo + bo (fp32) -- 64-tile
  gemm64<false><<<dim3(DMODEL / 64, (BATCH * NQ) / 64), 256, 0, stream>>>(
      attn, Wot, out, nullptr, bo, BATCH * NQ, DMODEL, INNER);
}